// Round 1
// baseline (87.682 us; speedup 1.0000x reference)
//
#include <hip/hip_runtime.h>
#include <math.h>

#define NN 207
#define BB 2
#define TT 864
#define LL 12
#define DD 96
#define PP 72
#define EPSF 1e-8f

// ---- K1: per-row gumbel scores -> top-k -> softmax -> Weff[i,d,l] to ws ----
// grid = NN blocks x 256 threads. Latency-bound but tiny (~954 KB written).
__global__ __launch_bounds__(256) void weff_kernel(
    const float* __restrict__ adj,    // (N,N)
    const float* __restrict__ noise,  // (N,N)
    const float* __restrict__ W,      // (D,N,L)
    const int*   __restrict__ kptr,   // scalar k
    float*       __restrict__ weff)   // (N,D,L) workspace
{
    __shared__ float s_score[NN];
    __shared__ float s_topS[32];
    __shared__ int   s_topI[32];

    const int i   = blockIdx.x;
    const int tid = threadIdx.x;
    const int kk  = min(*kptr, 32);

    // Phase 1: gumbel-perturbed log-scores for row i
    if (tid < NN) {
        float a = fmaxf(adj[i * NN + tid], 0.0f) + EPSF;
        float u = noise[i * NN + tid] + EPSF;
        s_score[tid] = logf(a) - logf(-logf(u));
    }
    __syncthreads();

    // Phase 2: wave 0 does iterative top-k + softmax over kept entries
    if (tid < 64) {
        const int lane = tid;
        float v[4], orig[4];
        #pragma unroll
        for (int q = 0; q < 4; ++q) {
            int c = lane + 64 * q;
            v[q] = (c < NN) ? s_score[c] : -INFINITY;
            orig[q] = v[q];
        }
        float m = 0.0f, myv = 0.0f; int myi = 0;
        for (int it = 0; it < kk; ++it) {
            float bv = v[0]; int bi = lane;
            #pragma unroll
            for (int q = 1; q < 4; ++q)
                if (v[q] > bv) { bv = v[q]; bi = lane + 64 * q; }
            #pragma unroll
            for (int off = 32; off > 0; off >>= 1) {
                float ov = __shfl_xor(bv, off);
                int   oi = __shfl_xor(bi, off);
                if (ov > bv || (ov == bv && oi < bi)) { bv = ov; bi = oi; }
            }
            if (it == 0) m = bv;                     // softmax max = top-1
            if (lane == it) { myv = bv; myi = bi; }  // lane `it` owns winner `it`
            if ((bi & 63) == lane) v[bi >> 6] = -INFINITY;
        }
        float se = 0.0f;
        #pragma unroll
        for (int q = 0; q < 4; ++q) {
            int c = lane + 64 * q;
            if (c < NN) se += expf(orig[q] - m);
        }
        #pragma unroll
        for (int off = 32; off > 0; off >>= 1) se += __shfl_xor(se, off);
        if (lane < kk) {                             // se, m wave-uniform here
            s_topS[lane] = expf(myv - m) / se;
            s_topI[lane] = myi;
        }
    }
    __syncthreads();

    // Phase 3: Weff[d][l] = sum_t prob[t] * W[d, idx[t], l] -> global ws
    {
        const float4* W4  = (const float4*)W;            // (D*N) rows of 3 float4
        float4*       wf4 = (float4*)weff + i * (DD * 3);
        for (int e = tid; e < DD * 3; e += 256) {        // 288 float4 elems
            int d = e / 3, c = e - d * 3;
            float4 acc = {0.f, 0.f, 0.f, 0.f};
            for (int t = 0; t < kk; ++t) {
                float s  = s_topS[t];
                float4 w = W4[(d * NN + s_topI[t]) * 3 + c];
                acc.x += s * w.x; acc.y += s * w.y;
                acc.z += s * w.z; acc.w += s * w.w;
            }
            wf4[e] = acc;
        }
    }
}

// ---- K2: out[b,i,d,p] = bias[d] + sum_l x[b,i,p*L+l] * Weff[i,d,l] ----
// One thread per output float4 (p-quarter). 715392 threads = 2795 blocks:
// ~11 blocks/CU -> full occupancy, no LDS, weights in 12 regs, coalesced stores.
__global__ __launch_bounds__(256) void out_kernel(
    const float* __restrict__ x,     // (B,N,1,T)
    const float* __restrict__ weff,  // (N,D,L)
    const float* __restrict__ bias,  // (D,)
    float*       __restrict__ out)   // (B,N,D,P)
{
    const unsigned TOTAL = BB * NN * DD * (PP / 4);      // 715392
    unsigned e = blockIdx.x * 256u + threadIdx.x;
    if (e >= TOTAL) return;

    unsigned c  = e % 18u;             // p-quarter index
    unsigned r  = e / 18u;             // (b*N+i)*D + d
    unsigned d  = r % (unsigned)DD;
    unsigned bi = r / (unsigned)DD;    // b*N + i
    unsigned i  = bi % (unsigned)NN;

    const float4* x4 = (const float4*)x + (size_t)bi * (TT / 4) + c * 12u;
    const float4* w4 = (const float4*)weff + ((size_t)i * DD + d) * 3u;

    float4 w0 = w4[0], w1 = w4[1], w2 = w4[2];
    float  bd = bias[d];

    float o[4];
    #pragma unroll
    for (int q = 0; q < 4; ++q) {
        float4 a0 = x4[q * 3 + 0];
        float4 a1 = x4[q * 3 + 1];
        float4 a2 = x4[q * 3 + 2];
        float s = bd;
        s += a0.x * w0.x; s += a0.y * w0.y; s += a0.z * w0.z; s += a0.w * w0.w;
        s += a1.x * w1.x; s += a1.y * w1.y; s += a1.z * w1.z; s += a1.w * w1.w;
        s += a2.x * w2.x; s += a2.y * w2.y; s += a2.z * w2.z; s += a2.w * w2.w;
        o[q] = s;
    }
    float4 val = {o[0], o[1], o[2], o[3]};
    ((float4*)out)[e] = val;
}

extern "C" void kernel_launch(void* const* d_in, const int* in_sizes, int n_in,
                              void* d_out, int out_size, void* d_ws, size_t ws_size,
                              hipStream_t stream) {
    const float* x     = (const float*)d_in[0];
    const float* adj   = (const float*)d_in[1];
    const float* noise = (const float*)d_in[2];
    const float* W     = (const float*)d_in[3];
    const float* bias  = (const float*)d_in[4];
    const int*   kptr  = (const int*)d_in[5];
    float* out  = (float*)d_out;
    float* weff = (float*)d_ws;   // needs N*D*L*4 = 953,856 B of workspace

    weff_kernel<<<NN, 256, 0, stream>>>(adj, noise, W, kptr, weff);

    const int total4 = BB * NN * DD * (PP / 4);          // 715392
    out_kernel<<<(total4 + 255) / 256, 256, 0, stream>>>(x, weff, bias, out);
}

// Round 2
// 87.185 us; speedup vs baseline: 1.0057x; 1.0057x over previous
//
#include <hip/hip_runtime.h>
#include <math.h>

#define NN 207
#define BB 2
#define TT 864
#define LL 12
#define DD 96
#define PP 72
#define EPSF 1e-8f

// Single launch: score -> top-k -> softmax -> Weff (LDS) -> output.
// Phase 4 reads x directly from global (L1-resident 3.5 KB row, contiguous
// per 18-lane group) instead of LDS: the old s_x path had a 192 B/lane
// stride -> banks {0,16} only -> 4-8x serialization at 1 wave/SIMD.
__global__ __launch_bounds__(512) void stpe_fused_kernel(
    const float* __restrict__ x,      // (B,N,1,T)
    const float* __restrict__ adj,    // (N,N)
    const float* __restrict__ noise,  // (N,N)
    const float* __restrict__ W,      // (D,N,L)
    const float* __restrict__ bias,   // (D,)
    const int*   __restrict__ kptr,   // scalar k
    float*       __restrict__ out)    // (B,N,D,P)
{
    __shared__ float s_score[NN];
    __shared__ float s_weff[DD * LL];
    __shared__ float s_topS[32];
    __shared__ int   s_topI[32];

    const int i   = blockIdx.x;      // graph row
    const int tid = threadIdx.x;
    const int kk  = min(*kptr, 32);

    // ---- Phase 1: Gumbel scores for row i ----
    if (tid < NN) {
        float a = fmaxf(adj[i * NN + tid], 0.0f) + EPSF;
        float u = noise[i * NN + tid] + EPSF;
        s_score[tid] = logf(a) - logf(-logf(u));
    }
    __syncthreads();

    // ---- Phase 2: wave 0 does top-k + softmax; writes final probs ----
    if (tid < 64) {
        const int lane = tid;
        float v[4], orig[4];
        #pragma unroll
        for (int q = 0; q < 4; ++q) {
            int c = lane + 64 * q;
            v[q] = (c < NN) ? s_score[c] : -INFINITY;
            orig[q] = v[q];
        }
        float m = 0.0f, myv = 0.0f; int myi = 0;
        for (int it = 0; it < kk; ++it) {
            float bv = v[0]; int bi = lane;
            #pragma unroll
            for (int q = 1; q < 4; ++q)
                if (v[q] > bv) { bv = v[q]; bi = lane + 64 * q; }
            #pragma unroll
            for (int off = 32; off > 0; off >>= 1) {
                float ov = __shfl_xor(bv, off);
                int   oi = __shfl_xor(bi, off);
                if (ov > bv || (ov == bv && oi < bi)) { bv = ov; bi = oi; }
            }
            if (it == 0) m = bv;                     // softmax max = top-1
            if (lane == it) { myv = bv; myi = bi; }  // lane `it` owns winner `it`
            if ((bi & 63) == lane) v[bi >> 6] = -INFINITY;
        }
        float se = 0.0f;
        #pragma unroll
        for (int q = 0; q < 4; ++q) {
            int c = lane + 64 * q;
            if (c < NN) se += expf(orig[q] - m);
        }
        #pragma unroll
        for (int off = 32; off > 0; off >>= 1) se += __shfl_xor(se, off);
        if (lane < kk) {                             // se, m wave-uniform here
            s_topS[lane] = expf(myv - m) / se;
            s_topI[lane] = myi;
        }
    }
    __syncthreads();

    // ---- Phase 3: Weff[d][l] = sum_t prob[t] * W[d, idx[t], l] (float4) ----
    {
        const float4* W4 = (const float4*)W;       // (D*N) rows of 3 float4
        float4* weff4 = (float4*)s_weff;
        for (int e = tid; e < DD * 3; e += 512) {  // 288 float4 elems
            int d = e / 3, c = e - d * 3;
            float4 acc = {0.f, 0.f, 0.f, 0.f};
            for (int t = 0; t < kk; ++t) {
                float s  = s_topS[t];
                float4 w = W4[(d * NN + s_topI[t]) * 3 + c];
                acc.x += s * w.x; acc.y += s * w.y;
                acc.z += s * w.z; acc.w += s * w.w;
            }
            weff4[e] = acc;
        }
    }
    __syncthreads();

    // ---- Phase 4: out[b,i,d,p] = bias[d] + sum_l x[b,i,p*L+l]*Weff[d,l] ----
    // x from global (coalesced float4, L1-warm); Weff from LDS (<=4-way
    // broadcast, free); one float4 of p per loop element.
    {
        const float4* xbase = (const float4*)x;    // rows of 216 float4
        float4*       out4  = (float4*)out;
        for (int e = tid; e < BB * DD * (PP / 4); e += 512) {
            int b = e / (DD * (PP / 4));
            int r = e - b * (DD * (PP / 4));
            int d = r / (PP / 4);
            int c = r - d * (PP / 4);
            const float4* x4 = xbase + (size_t)(b * NN + i) * (TT / 4) + c * 12;
            const float4* w4 = (const float4*)&s_weff[d * LL];
            float4 w0 = w4[0], w1 = w4[1], w2 = w4[2];
            float  bd = bias[d];
            float o[4];
            #pragma unroll
            for (int q = 0; q < 4; ++q) {
                float4 a0 = x4[q * 3 + 0];
                float4 a1 = x4[q * 3 + 1];
                float4 a2 = x4[q * 3 + 2];
                float s = bd;
                s += a0.x * w0.x; s += a0.y * w0.y; s += a0.z * w0.z; s += a0.w * w0.w;
                s += a1.x * w1.x; s += a1.y * w1.y; s += a1.z * w1.z; s += a1.w * w1.w;
                s += a2.x * w2.x; s += a2.y * w2.y; s += a2.z * w2.z; s += a2.w * w2.w;
                o[q] = s;
            }
            float4 val = {o[0], o[1], o[2], o[3]};
            out4[((size_t)(b * NN + i) * DD + d) * (PP / 4) + c] = val;
        }
    }
}

extern "C" void kernel_launch(void* const* d_in, const int* in_sizes, int n_in,
                              void* d_out, int out_size, void* d_ws, size_t ws_size,
                              hipStream_t stream) {
    const float* x     = (const float*)d_in[0];
    const float* adj   = (const float*)d_in[1];
    const float* noise = (const float*)d_in[2];
    const float* W     = (const float*)d_in[3];
    const float* bias  = (const float*)d_in[4];
    const int*   kptr  = (const int*)d_in[5];
    float* out = (float*)d_out;

    stpe_fused_kernel<<<NN, 512, 0, stream>>>(x, adj, noise, W, bias, kptr, out);
}